// Round 4
// baseline (25133.453 us; speedup 1.0000x reference)
//
#include <hip/hip_runtime.h>
#include <stdint.h>

typedef __bf16 bf16x8 __attribute__((ext_vector_type(8)));
typedef float f32x4 __attribute__((ext_vector_type(4)));
typedef unsigned short ushort_t;

__device__ __forceinline__ float b2f(ushort_t u) {
  union { unsigned int i; float f; } x; x.i = ((unsigned int)u) << 16; return x.f;
}
__device__ __forceinline__ ushort_t f2b(float f) {
  union { float f; unsigned int i; } x; x.f = f;
  unsigned int r = x.i + 0x7fffu + ((x.i >> 16) & 1u);
  return (ushort_t)(r >> 16);
}

// ---------------------------------------------------------------------------
// f32 -> bf16 downcast, 4 elements/thread. n4 = element_count / 4.
// ---------------------------------------------------------------------------
__global__ __launch_bounds__(256) void cvt_f32_bf16(const float* __restrict__ src,
                                                    ushort_t* __restrict__ dst,
                                                    int n4)
{
  const int i = blockIdx.x * 256 + threadIdx.x;
  if (i >= n4) return;
  const float4 v = ((const float4*)src)[i];
  ushort4 o;
  o.x = f2b(v.x); o.y = f2b(v.y); o.z = f2b(v.z); o.w = f2b(v.w);
  ((ushort4*)dst)[i] = o;
}

// ---------------------------------------------------------------------------
// dec chunk (bf16 [T*64,128]) from f32 mels: row gr = t0*64+(i>>5);
// dec[gr] = (gr<64) ? 0 : bf16(mels[gr-64]). 4 elems/thread, n4 = T*2048.
// ---------------------------------------------------------------------------
__global__ __launch_bounds__(256) void build_decin(const float* __restrict__ mels,
                                                   ushort_t* __restrict__ dec,
                                                   int t0, int n4)
{
  const int i = blockIdx.x * 256 + threadIdx.x;
  if (i >= n4) return;
  const int gr = t0 * 64 + (i >> 5);
  ushort4 o;
  if (gr < 64) {
    o.x = o.y = o.z = o.w = 0;
  } else {
    const float4 v = ((const float4*)mels)[(size_t)(gr - 64) * 32 + (i & 31)];
    o.x = f2b(v.x); o.y = f2b(v.y); o.z = f2b(v.z); o.w = f2b(v.w);
  }
  ((ushort4*)dec)[i] = o;
}

// ---------------------------------------------------------------------------
// C = [A1|A2] @ B^T + bias1 + bias2 (f32 biases), optional relu.
// A,B bf16; f32 accumulate; C written bf16 (out_f32=0) or f32 (out_f32=1).
// B row-major [N, K1+K2]. Tiles 128x128, BK=64, 4 waves (2x2 of 64x64).
// Staging: per-lane bf16x8 global loads -> LDS rows padded to 72 elems.
// ---------------------------------------------------------------------------
__global__ __launch_bounds__(256) void gemm_bt(
    const ushort_t* __restrict__ A1, int lda1, int K1,
    const ushort_t* __restrict__ A2, int lda2, int K2,
    const ushort_t* __restrict__ B,
    const float* __restrict__ bias1, const float* __restrict__ bias2,
    void* __restrict__ C, int ldc, int relu, int out_f32)
{
  __shared__ __align__(16) ushort_t As[128 * 72];
  __shared__ __align__(16) ushort_t Bs[128 * 72];
  const int tid = threadIdx.x;
  const int wave = tid >> 6, lane = tid & 63;
  const int bm = blockIdx.x, bn = blockIdx.y;
  const int wm = (wave & 1) * 64, wn = (wave >> 1) * 64;
  const int l15 = lane & 15, quad = lane >> 4;
  const int ldb = K1 + K2;

  f32x4 acc[4][4] = {};

  const int kb1 = K1 >> 6, kb2 = K2 >> 6;
  for (int kb = 0; kb < kb1 + kb2; ++kb) {
    const bool ph2 = (kb >= kb1);
    const ushort_t* Aptr = ph2 ? A2 : A1;
    const int lda = ph2 ? lda2 : lda1;
    const int k0 = ph2 ? ((kb - kb1) << 6) : (kb << 6);
    const int bk0 = ph2 ? (K1 + k0) : k0;

#pragma unroll
    for (int s = 0; s < 4; ++s) {
      const int ch = s * 256 + tid;
      const int row = ch >> 3, pos = ch & 7;
      const bf16x8 av = *(const bf16x8*)(Aptr + (size_t)(bm * 128 + row) * lda
                                         + k0 + pos * 8);
      *(bf16x8*)(As + row * 72 + pos * 8) = av;
      const bf16x8 bv = *(const bf16x8*)(B + (size_t)(bn * 128 + row) * ldb
                                         + bk0 + pos * 8);
      *(bf16x8*)(Bs + row * 72 + pos * 8) = bv;
    }
    __syncthreads();

#pragma unroll
    for (int ks = 0; ks < 2; ++ks) {
      bf16x8 af[4], bfr[4];
      const int c = ks * 4 + quad;
#pragma unroll
      for (int mt = 0; mt < 4; ++mt)
        af[mt] = *(const bf16x8*)(As + (wm + mt * 16 + l15) * 72 + c * 8);
#pragma unroll
      for (int nt = 0; nt < 4; ++nt)
        bfr[nt] = *(const bf16x8*)(Bs + (wn + nt * 16 + l15) * 72 + c * 8);
#pragma unroll
      for (int mt = 0; mt < 4; ++mt)
#pragma unroll
        for (int nt = 0; nt < 4; ++nt)
          acc[mt][nt] = __builtin_amdgcn_mfma_f32_16x16x32_bf16(
              af[mt], bfr[nt], acc[mt][nt], 0, 0, 0);
    }
    __syncthreads();
  }

#pragma unroll
  for (int nt = 0; nt < 4; ++nt) {
    const int n = bn * 128 + wn + nt * 16 + l15;
    float bsum = 0.f;
    if (bias1) bsum += bias1[n];
    if (bias2) bsum += bias2[n];
#pragma unroll
    for (int mt = 0; mt < 4; ++mt) {
#pragma unroll
      for (int r = 0; r < 4; ++r) {
        const int m = bm * 128 + wm + mt * 16 + quad * 4 + r;
        float v = acc[mt][nt][r] + bsum;
        if (relu) v = fmaxf(v, 0.f);
        if (out_f32) ((float*)C)[(size_t)m * ldc + n] = v;
        else         ((ushort_t*)C)[(size_t)m * ldc + n] = f2b(v);
      }
    }
  }
}

// ---------------------------------------------------------------------------
// One LSTM step. 64 blocks x 256 threads (4 waves). Block nb owns d-slice
// [nb*16, nb*16+16) for all 4 gates; wave g computes gate g over full K=1024.
// h_prev / W_hh fragments read directly from global (L2-resident across
// launches). f32 partials scattered to 16 KB LDS; cell update in-block.
// ---------------------------------------------------------------------------
__global__ __launch_bounds__(256) void lstm_step(
    const ushort_t* __restrict__ gx_t,   // [64, 4096] bf16, this step
    const ushort_t* __restrict__ Whh,    // [4096, 1024] bf16
    const ushort_t* __restrict__ h_prev, // [64, 1024] bf16
    ushort_t* __restrict__ h_out,        // [64, 1024] bf16
    float* __restrict__ cst)             // [64, 1024] f32, persistent
{
  __shared__ __align__(16) float gsm[4 * 64 * 16];   // [g][b][dl] = 16 KB
  const int tid = threadIdx.x;
  const int g = tid >> 6, lane = tid & 63;
  const int l15 = lane & 15, quad = lane >> 4;
  const int ds = blockIdx.x * 16;

  f32x4 acc[4] = {};
  const ushort_t* wrow = Whh + ((size_t)(g * 1024 + ds + l15)) * 1024 + quad * 8;
  const ushort_t* hrow = h_prev + quad * 8;

#pragma unroll 4
  for (int ks = 0; ks < 32; ++ks) {
    const bf16x8 bfr = *(const bf16x8*)(wrow + ks * 32);
#pragma unroll
    for (int i = 0; i < 4; ++i) {
      const bf16x8 afr =
          *(const bf16x8*)(hrow + (size_t)(i * 16 + l15) * 1024 + ks * 32);
      acc[i] = __builtin_amdgcn_mfma_f32_16x16x32_bf16(afr, bfr, acc[i], 0, 0, 0);
    }
  }

  // C/D: col = lane&15 (local d), row = quad*4+r (batch within 16-row tile)
#pragma unroll
  for (int i = 0; i < 4; ++i) {
#pragma unroll
    for (int r = 0; r < 4; ++r) {
      const int b = i * 16 + quad * 4 + r;
      gsm[g * 1024 + b * 16 + l15] = acc[i][r];
    }
  }
  __syncthreads();

  for (int e = tid; e < 1024; e += 256) {
    const int b = e >> 4, dl = e & 15;
    const int d = ds + dl;
    const float gi = gsm[0 * 1024 + e] + b2f(gx_t[b * 4096 + 0 * 1024 + d]);
    const float gf = gsm[1 * 1024 + e] + b2f(gx_t[b * 4096 + 1 * 1024 + d]);
    const float gg = gsm[2 * 1024 + e] + b2f(gx_t[b * 4096 + 2 * 1024 + d]);
    const float go = gsm[3 * 1024 + e] + b2f(gx_t[b * 4096 + 3 * 1024 + d]);
    const float si = 1.f / (1.f + __expf(-gi));
    const float sf = 1.f / (1.f + __expf(-gf));
    const float so = 1.f / (1.f + __expf(-go));
    const float tg = tanhf(gg);
    const float cn = sf * cst[b * 1024 + d] + si * tg;
    cst[b * 1024 + d] = cn;
    h_out[b * 1024 + d] = f2b(so * tanhf(cn));
  }
}

extern "C" void kernel_launch(void* const* d_in, const int* in_sizes, int n_in,
                              void* d_out, int out_size, void* d_ws, size_t ws_size,
                              hipStream_t stream) {
  // All inputs are float32 (reference dtype); internal compute is bf16.
  const float* enc   = (const float*)d_in[0];   // [1000,64,512]
  const float* mels  = (const float*)d_in[1];   // [1000,64,128]
  const float* preW1 = (const float*)d_in[2];   // [256,128]
  const float* preb1 = (const float*)d_in[3];
  const float* preW2 = (const float*)d_in[4];   // [256,256]
  const float* preb2 = (const float*)d_in[5];
  const float* Wih   = (const float*)d_in[6];   // [4096,768]
  const float* Whh   = (const float*)d_in[7];   // [4096,1024]
  const float* bih   = (const float*)d_in[8];
  const float* bhh   = (const float*)d_in[9];
  const float* projW = (const float*)d_in[10];  // [128,1536]
  const float* projb = (const float*)d_in[11];
  float* out = (float*)d_out;                   // [1000,64,128] f32

  // chunk length T: largest even divisor of 1000 whose buffers fit ws_size
  const size_t fixedB = 32768 * 2 + 65536 * 2 + 3145728 * 2 + 4194304 * 2
                      + 196608 * 2 + 262144 + 65536;  // weights + cst + slack
  const int cand[5] = {200, 100, 50, 10, 2};
  int T = 2;
  for (int ci = 0; ci < 5; ++ci) {
    const int t = cand[ci];
    size_t need = fixedB
                + (size_t)t * 524288            // gates bf16 [T*64,4096]
                + (size_t)t * 16384             // decin bf16 [T*64,128]
                + (size_t)t * 65536             // enc_c bf16 [T*64,512]
                + (size_t)t * 32768 * 2         // x1,x2 bf16 [T*64,256]
                + (size_t)(t + 1) * 131072;     // hs bf16 [(T+1)*64,1024]
    if (need <= ws_size) { T = t; break; }
  }

  char* ws = (char*)d_ws;
  size_t off = 0;
  auto carve = [&](size_t bytes) {
    char* p = ws + off;
    off += (bytes + 255) & ~(size_t)255;
    return p;
  };
  ushort_t* wW1  = (ushort_t*)carve(32768 * 2);
  ushort_t* wW2  = (ushort_t*)carve(65536 * 2);
  ushort_t* wIh  = (ushort_t*)carve(3145728 * 2);
  ushort_t* wHh  = (ushort_t*)carve(4194304 * 2);
  ushort_t* wPj  = (ushort_t*)carve(196608 * 2);
  float*    cst  = (float*)carve(262144);
  ushort_t* gates = (ushort_t*)carve((size_t)T * 524288);
  ushort_t* decin = (ushort_t*)carve((size_t)T * 16384);
  ushort_t* enc_c = (ushort_t*)carve((size_t)T * 65536);
  ushort_t* x1    = (ushort_t*)carve((size_t)T * 32768);
  ushort_t* x2    = (ushort_t*)carve((size_t)T * 32768);
  ushort_t* hs    = (ushort_t*)carve((size_t)(T + 1) * 131072);

  // one-time weight downcasts
  cvt_f32_bf16<<<32, 256, 0, stream>>>(preW1, wW1, 8192);
  cvt_f32_bf16<<<64, 256, 0, stream>>>(preW2, wW2, 16384);
  cvt_f32_bf16<<<3072, 256, 0, stream>>>(Wih, wIh, 786432);
  cvt_f32_bf16<<<4096, 256, 0, stream>>>(Whh, wHh, 1048576);
  cvt_f32_bf16<<<192, 256, 0, stream>>>(projW, wPj, 49152);

  hipMemsetAsync(hs, 0, 131072, stream);    // h0 = 0 (slot 0)
  hipMemsetAsync(cst, 0, 262144, stream);   // c0 = 0

  const int nch = 1000 / T;
  const int Mb = (T * 64) / 128;            // M-blocks per chunk (T even)

  for (int c = 0; c < nch; ++c) {
    const int t0 = c * T;

    // per-chunk input downcasts
    cvt_f32_bf16<<<(T * 8192 + 255) / 256, 256, 0, stream>>>(
        enc + (size_t)t0 * 32768, enc_c, T * 8192);
    build_decin<<<T * 8, 256, 0, stream>>>(mels, decin, t0, T * 2048);

    // prenet 1: relu(decin @ W1^T + b1) -> x1 [T*64,256]
    gemm_bt<<<dim3(Mb, 2), 256, 0, stream>>>(decin, 128, 128, nullptr, 0, 0,
                                             wW1, preb1, nullptr, x1, 256, 1, 0);
    // prenet 2: relu(x1 @ W2^T + b2) -> x2 [T*64,256]
    gemm_bt<<<dim3(Mb, 2), 256, 0, stream>>>(x1, 256, 256, nullptr, 0, 0,
                                             wW2, preb2, nullptr, x2, 256, 1, 0);
    // gates_x = [x2|enc] @ W_ih^T + b_ih + b_hh -> [T*64,4096]
    gemm_bt<<<dim3(Mb, 32), 256, 0, stream>>>(x2, 256, 256, enc_c, 512, 512,
                                              wIh, bih, bhh, gates, 4096, 0, 0);
    // recurrence
    for (int s = 0; s < T; ++s) {
      lstm_step<<<64, 256, 0, stream>>>(gates + (size_t)s * 262144, wHh,
                                        hs + (size_t)s * 65536,
                                        hs + (size_t)(s + 1) * 65536, cst);
    }
    // projection: out_chunk = [hs|enc] @ projW^T + projb (f32 out)
    gemm_bt<<<dim3(Mb, 1), 256, 0, stream>>>(hs + 65536, 1024, 1024, enc_c,
                                             512, 512, wPj, projb, nullptr,
                                             out + (size_t)t0 * 8192, 128, 0, 1);
    // carry h into slot 0 for next chunk
    if (c + 1 < nch) {
      hipMemcpyAsync(hs, hs + (size_t)T * 65536, 131072,
                     hipMemcpyDeviceToDevice, stream);
    }
  }
}

// Round 5
// 23613.484 us; speedup vs baseline: 1.0644x; 1.0644x over previous
//
#include <hip/hip_runtime.h>
#include <stdint.h>

typedef __bf16 bf16x8 __attribute__((ext_vector_type(8)));
typedef float f32x4 __attribute__((ext_vector_type(4)));
typedef unsigned short ushort_t;

__device__ __forceinline__ float b2f(ushort_t u) {
  union { unsigned int i; float f; } x; x.i = ((unsigned int)u) << 16; return x.f;
}
__device__ __forceinline__ ushort_t f2b(float f) {
  union { float f; unsigned int i; } x; x.f = f;
  unsigned int r = x.i + 0x7fffu + ((x.i >> 16) & 1u);
  return (ushort_t)(r >> 16);
}

// ---------------------------------------------------------------------------
// f32 -> bf16 downcast, 4 elements/thread. n4 = element_count / 4.
// ---------------------------------------------------------------------------
__global__ __launch_bounds__(256) void cvt_f32_bf16(const float* __restrict__ src,
                                                    ushort_t* __restrict__ dst,
                                                    int n4)
{
  const int i = blockIdx.x * 256 + threadIdx.x;
  if (i >= n4) return;
  const float4 v = ((const float4*)src)[i];
  ushort4 o;
  o.x = f2b(v.x); o.y = f2b(v.y); o.z = f2b(v.z); o.w = f2b(v.w);
  ((ushort4*)dst)[i] = o;
}

// ---------------------------------------------------------------------------
// dec chunk (bf16 [T*64,128]) from f32 mels: row gr = t0*64+(i>>5);
// dec[gr] = (gr<64) ? 0 : bf16(mels[gr-64]). 4 elems/thread, n4 = T*2048.
// ---------------------------------------------------------------------------
__global__ __launch_bounds__(256) void build_decin(const float* __restrict__ mels,
                                                   ushort_t* __restrict__ dec,
                                                   int t0, int n4)
{
  const int i = blockIdx.x * 256 + threadIdx.x;
  if (i >= n4) return;
  const int gr = t0 * 64 + (i >> 5);
  ushort4 o;
  if (gr < 64) {
    o.x = o.y = o.z = o.w = 0;
  } else {
    const float4 v = ((const float4*)mels)[(size_t)(gr - 64) * 32 + (i & 31)];
    o.x = f2b(v.x); o.y = f2b(v.y); o.z = f2b(v.z); o.w = f2b(v.w);
  }
  ((ushort4*)dec)[i] = o;
}

// ---------------------------------------------------------------------------
// C = [A1|A2] @ B^T + bias1 + bias2 (f32 biases), optional relu.
// A,B bf16; f32 accumulate; C written bf16 (out_f32=0) or f32 (out_f32=1).
// Tiles 128x128, BK=64, 4 waves. LDS rows padded to 72 elems.
// ---------------------------------------------------------------------------
__global__ __launch_bounds__(256) void gemm_bt(
    const ushort_t* __restrict__ A1, int lda1, int K1,
    const ushort_t* __restrict__ A2, int lda2, int K2,
    const ushort_t* __restrict__ B,
    const float* __restrict__ bias1, const float* __restrict__ bias2,
    void* __restrict__ C, int ldc, int relu, int out_f32)
{
  __shared__ __align__(16) ushort_t As[128 * 72];
  __shared__ __align__(16) ushort_t Bs[128 * 72];
  const int tid = threadIdx.x;
  const int wave = tid >> 6, lane = tid & 63;
  const int bm = blockIdx.x, bn = blockIdx.y;
  const int wm = (wave & 1) * 64, wn = (wave >> 1) * 64;
  const int l15 = lane & 15, quad = lane >> 4;
  const int ldb = K1 + K2;

  f32x4 acc[4][4] = {};

  const int kb1 = K1 >> 6, kb2 = K2 >> 6;
  for (int kb = 0; kb < kb1 + kb2; ++kb) {
    const bool ph2 = (kb >= kb1);
    const ushort_t* Aptr = ph2 ? A2 : A1;
    const int lda = ph2 ? lda2 : lda1;
    const int k0 = ph2 ? ((kb - kb1) << 6) : (kb << 6);
    const int bk0 = ph2 ? (K1 + k0) : k0;

#pragma unroll
    for (int s = 0; s < 4; ++s) {
      const int ch = s * 256 + tid;
      const int row = ch >> 3, pos = ch & 7;
      const bf16x8 av = *(const bf16x8*)(Aptr + (size_t)(bm * 128 + row) * lda
                                         + k0 + pos * 8);
      *(bf16x8*)(As + row * 72 + pos * 8) = av;
      const bf16x8 bv = *(const bf16x8*)(B + (size_t)(bn * 128 + row) * ldb
                                         + bk0 + pos * 8);
      *(bf16x8*)(Bs + row * 72 + pos * 8) = bv;
    }
    __syncthreads();

#pragma unroll
    for (int ks = 0; ks < 2; ++ks) {
      bf16x8 af[4], bfr[4];
      const int c = ks * 4 + quad;
#pragma unroll
      for (int mt = 0; mt < 4; ++mt)
        af[mt] = *(const bf16x8*)(As + (wm + mt * 16 + l15) * 72 + c * 8);
#pragma unroll
      for (int nt = 0; nt < 4; ++nt)
        bfr[nt] = *(const bf16x8*)(Bs + (wn + nt * 16 + l15) * 72 + c * 8);
#pragma unroll
      for (int mt = 0; mt < 4; ++mt)
#pragma unroll
        for (int nt = 0; nt < 4; ++nt)
          acc[mt][nt] = __builtin_amdgcn_mfma_f32_16x16x32_bf16(
              af[mt], bfr[nt], acc[mt][nt], 0, 0, 0);
    }
    __syncthreads();
  }

#pragma unroll
  for (int nt = 0; nt < 4; ++nt) {
    const int n = bn * 128 + wn + nt * 16 + l15;
    float bsum = 0.f;
    if (bias1) bsum += bias1[n];
    if (bias2) bsum += bias2[n];
#pragma unroll
    for (int mt = 0; mt < 4; ++mt) {
#pragma unroll
      for (int r = 0; r < 4; ++r) {
        const int m = bm * 128 + wm + mt * 16 + quad * 4 + r;
        float v = acc[mt][nt][r] + bsum;
        if (relu) v = fmaxf(v, 0.f);
        if (out_f32) ((float*)C)[(size_t)m * ldc + n] = v;
        else         ((ushort_t*)C)[(size_t)m * ldc + n] = f2b(v);
      }
    }
  }
}

// ---------------------------------------------------------------------------
// Persistent LSTM recurrence over T steps. 64 blocks x 256 threads
// (1 block/CU, all co-resident). Block nb owns d-slice [nb*16,nb*16+16) of
// all 4 gates. Wave g holds its W_hh gate-slice as 32 B-fragments in
// REGISTERS (128 VGPR, loaded once). Per step: grid barrier -> stage h
// (4 x 32KB K-quarters, XOR-swizzled) into LDS -> 128 MFMA/wave ->
// gate combine in LDS -> cell update -> h slice store to hs[s+1].
// Grid barrier: sense-reversing, device(agent)-scope atomics.
// ---------------------------------------------------------------------------
__global__ __launch_bounds__(256, 1) void lstm_persist(
    const ushort_t* __restrict__ gates,  // [T*64, 4096] bf16
    const ushort_t* __restrict__ Whh,    // [4096, 1024] bf16
    ushort_t* __restrict__ hs,           // [(T+1)*64, 1024] bf16
    float* __restrict__ cst,             // [64, 1024] f32, persistent
    int T, int* __restrict__ bar)        // bar[0]=cnt, bar[1]=gen
{
  __shared__ __align__(16) ushort_t hsm[64 * 256];   // one K-quarter, 32 KB
  __shared__ __align__(16) float gsm[4 * 64 * 16];   // [g][b][dl], 16 KB
  const int tid = threadIdx.x;
  const int g = tid >> 6, lane = tid & 63;
  const int l15 = lane & 15, quad = lane >> 4;
  const int ds = blockIdx.x * 16;

  // preload W fragments: wave g, rows g*1024+ds+l15, all K. 128 VGPRs.
  bf16x8 warr[32];
  {
    const ushort_t* wrow =
        Whh + ((size_t)(g * 1024 + ds + l15)) * 1024 + quad * 8;
#pragma unroll
    for (int ks = 0; ks < 32; ++ks)
      warr[ks] = *(const bf16x8*)(wrow + ks * 32);
  }

  for (int s = 0; s < T; ++s) {
    if (s > 0) {
      // grid barrier: h[s] slices from all blocks must be globally visible
      __syncthreads();
      if (tid == 0) {
        const int gv = __hip_atomic_load(bar + 1, __ATOMIC_RELAXED,
                                         __HIP_MEMORY_SCOPE_AGENT);
        __threadfence();
        const int a = __hip_atomic_fetch_add(bar, 1, __ATOMIC_ACQ_REL,
                                             __HIP_MEMORY_SCOPE_AGENT);
        if (a == 63) {
          __hip_atomic_store(bar, 0, __ATOMIC_RELAXED,
                             __HIP_MEMORY_SCOPE_AGENT);
          __hip_atomic_fetch_add(bar + 1, 1, __ATOMIC_RELEASE,
                                 __HIP_MEMORY_SCOPE_AGENT);
        } else {
          while (__hip_atomic_load(bar + 1, __ATOMIC_ACQUIRE,
                                   __HIP_MEMORY_SCOPE_AGENT) == gv)
            __builtin_amdgcn_s_sleep(2);
        }
      }
      __syncthreads();
    }

    const ushort_t* hsrc = hs + (size_t)s * 65536;
    f32x4 acc[4] = {};

#pragma unroll
    for (int ph = 0; ph < 4; ++ph) {
      // stage K-quarter [64 rows x 256 elems], XOR-swizzled 16B chunks
#pragma unroll
      for (int jj = 0; jj < 8; ++jj) {
        const int idx = jj * 256 + tid;
        const int m = idx >> 5, c = idx & 31;
        const int p = (c & ~7) | ((c ^ m) & 7);
        *(bf16x8*)(hsm + m * 256 + p * 8) =
            *(const bf16x8*)(hsrc + m * 1024 + ph * 256 + c * 8);
      }
      __syncthreads();
#pragma unroll
      for (int ks = 0; ks < 8; ++ks) {
        const int c = ks * 4 + quad;
#pragma unroll
        for (int i = 0; i < 4; ++i) {
          const int m = i * 16 + l15;
          const int p = (c & ~7) | ((c ^ m) & 7);
          const bf16x8 afr = *(const bf16x8*)(hsm + m * 256 + p * 8);
          acc[i] = __builtin_amdgcn_mfma_f32_16x16x32_bf16(
              afr, warr[ph * 8 + ks], acc[i], 0, 0, 0);
        }
      }
      __syncthreads();
    }

    // gate combine: C/D col = l15 (local d), row = quad*4+r (batch in tile)
#pragma unroll
    for (int i = 0; i < 4; ++i)
#pragma unroll
      for (int r = 0; r < 4; ++r)
        gsm[g * 1024 + (i * 16 + quad * 4 + r) * 16 + l15] = acc[i][r];
    __syncthreads();

    const ushort_t* gx_t = gates + (size_t)s * 262144;
    ushort_t* hdst = hs + (size_t)(s + 1) * 65536;
#pragma unroll
    for (int e = tid; e < 1024; e += 256) {
      const int b = e >> 4, dl = e & 15;
      const int d = ds + dl;
      const float gi = gsm[0 * 1024 + e] + b2f(gx_t[b * 4096 + 0 * 1024 + d]);
      const float gf = gsm[1 * 1024 + e] + b2f(gx_t[b * 4096 + 1 * 1024 + d]);
      const float gg = gsm[2 * 1024 + e] + b2f(gx_t[b * 4096 + 2 * 1024 + d]);
      const float go = gsm[3 * 1024 + e] + b2f(gx_t[b * 4096 + 3 * 1024 + d]);
      const float si = 1.f / (1.f + __expf(-gi));
      const float sf = 1.f / (1.f + __expf(-gf));
      const float so = 1.f / (1.f + __expf(-go));
      const float tg = tanhf(gg);
      const float cn = sf * cst[b * 1024 + d] + si * tg;
      cst[b * 1024 + d] = cn;
      hdst[b * 1024 + d] = f2b(so * tanhf(cn));
    }
  }
}

extern "C" void kernel_launch(void* const* d_in, const int* in_sizes, int n_in,
                              void* d_out, int out_size, void* d_ws, size_t ws_size,
                              hipStream_t stream) {
  // All inputs are float32 (reference dtype); internal compute is bf16.
  const float* enc   = (const float*)d_in[0];   // [1000,64,512]
  const float* mels  = (const float*)d_in[1];   // [1000,64,128]
  const float* preW1 = (const float*)d_in[2];   // [256,128]
  const float* preb1 = (const float*)d_in[3];
  const float* preW2 = (const float*)d_in[4];   // [256,256]
  const float* preb2 = (const float*)d_in[5];
  const float* Wih   = (const float*)d_in[6];   // [4096,768]
  const float* Whh   = (const float*)d_in[7];   // [4096,1024]
  const float* bih   = (const float*)d_in[8];
  const float* bhh   = (const float*)d_in[9];
  const float* projW = (const float*)d_in[10];  // [128,1536]
  const float* projb = (const float*)d_in[11];
  float* out = (float*)d_out;                   // [1000,64,128] f32

  // chunk length T: largest even divisor of 1000 whose buffers fit ws_size
  const size_t fixedB = 32768 * 2 + 65536 * 2 + 3145728 * 2 + 4194304 * 2
                      + 196608 * 2 + 262144 + 65536;  // weights + cst + slack
  const int cand[5] = {200, 100, 50, 10, 2};
  int T = 2;
  for (int ci = 0; ci < 5; ++ci) {
    const int t = cand[ci];
    size_t need = fixedB
                + (size_t)t * 524288            // gates bf16 [T*64,4096]
                + (size_t)t * 16384             // decin bf16 [T*64,128]
                + (size_t)t * 65536             // enc_c bf16 [T*64,512]
                + (size_t)t * 32768 * 2         // x1,x2 bf16 [T*64,256]
                + (size_t)(t + 1) * 131072;     // hs bf16 [(T+1)*64,1024]
    if (need <= ws_size) { T = t; break; }
  }

  char* ws = (char*)d_ws;
  size_t off = 0;
  auto carve = [&](size_t bytes) {
    char* p = ws + off;
    off += (bytes + 255) & ~(size_t)255;
    return p;
  };
  ushort_t* wW1  = (ushort_t*)carve(32768 * 2);
  ushort_t* wW2  = (ushort_t*)carve(65536 * 2);
  ushort_t* wIh  = (ushort_t*)carve(3145728 * 2);
  ushort_t* wHh  = (ushort_t*)carve(4194304 * 2);
  ushort_t* wPj  = (ushort_t*)carve(196608 * 2);
  float*    cst  = (float*)carve(262144);
  int*      bar  = (int*)carve(256);
  ushort_t* gates = (ushort_t*)carve((size_t)T * 524288);
  ushort_t* decin = (ushort_t*)carve((size_t)T * 16384);
  ushort_t* enc_c = (ushort_t*)carve((size_t)T * 65536);
  ushort_t* x1    = (ushort_t*)carve((size_t)T * 32768);
  ushort_t* x2    = (ushort_t*)carve((size_t)T * 32768);
  ushort_t* hs    = (ushort_t*)carve((size_t)(T + 1) * 131072);

  // one-time weight downcasts
  cvt_f32_bf16<<<32, 256, 0, stream>>>(preW1, wW1, 8192);
  cvt_f32_bf16<<<64, 256, 0, stream>>>(preW2, wW2, 16384);
  cvt_f32_bf16<<<3072, 256, 0, stream>>>(Wih, wIh, 786432);
  cvt_f32_bf16<<<4096, 256, 0, stream>>>(Whh, wHh, 1048576);
  cvt_f32_bf16<<<192, 256, 0, stream>>>(projW, wPj, 49152);

  hipMemsetAsync(hs, 0, 131072, stream);    // h0 = 0 (slot 0)
  hipMemsetAsync(cst, 0, 262144, stream);   // c0 = 0
  hipMemsetAsync(bar, 0, 256, stream);      // barrier cnt/gen

  const int nch = 1000 / T;
  const int Mb = (T * 64) / 128;            // M-blocks per chunk (T even)

  for (int c = 0; c < nch; ++c) {
    const int t0 = c * T;

    // per-chunk input downcasts
    cvt_f32_bf16<<<(T * 8192 + 255) / 256, 256, 0, stream>>>(
        enc + (size_t)t0 * 32768, enc_c, T * 8192);
    build_decin<<<T * 8, 256, 0, stream>>>(mels, decin, t0, T * 2048);

    // prenet 1: relu(decin @ W1^T + b1) -> x1 [T*64,256]
    gemm_bt<<<dim3(Mb, 2), 256, 0, stream>>>(decin, 128, 128, nullptr, 0, 0,
                                             wW1, preb1, nullptr, x1, 256, 1, 0);
    // prenet 2: relu(x1 @ W2^T + b2) -> x2 [T*64,256]
    gemm_bt<<<dim3(Mb, 2), 256, 0, stream>>>(x1, 256, 256, nullptr, 0, 0,
                                             wW2, preb2, nullptr, x2, 256, 1, 0);
    // gates_x = [x2|enc] @ W_ih^T + b_ih + b_hh -> [T*64,4096]
    gemm_bt<<<dim3(Mb, 32), 256, 0, stream>>>(x2, 256, 256, enc_c, 512, 512,
                                              wIh, bih, bhh, gates, 4096, 0, 0);
    // recurrence: one persistent launch per chunk
    lstm_persist<<<64, 256, 0, stream>>>(gates, wHh, hs, cst, T, bar);

    // projection: out_chunk = [hs|enc] @ projW^T + projb (f32 out)
    gemm_bt<<<dim3(Mb, 1), 256, 0, stream>>>(hs + 65536, 1024, 1024, enc_c,
                                             512, 512, wPj, projb, nullptr,
                                             out + (size_t)t0 * 8192, 128, 0, 1);
    // carry h into slot 0 for next chunk
    if (c + 1 < nch) {
      hipMemcpyAsync(hs, hs + (size_t)T * 65536, 131072,
                     hipMemcpyDeviceToDevice, stream);
    }
  }
}